// Round 8
// baseline (579.491 us; speedup 1.0000x reference)
//
#include <hip/hip_runtime.h>
#include <hip/hip_bf16.h>

// FiLM block, MI355X. I/O fp32; compute bf16 MFMA (A=weights, B=tokens,
// C col=token), fp32 accum. R14 = R13 (passed, 71us) with the SH h-scratch
// ELIMINATED: the LN->next-layer h hand-off is a pure intra-wave quad
// permutation, done in registers via __shfl instead of an LDS round-trip.
//   dest lane (lo16,q), frag word s of bh[ks] = packed pair pk[r-pair s&1]
//   of nt' = 2ks+(q>>1), read from lane lo16 + 16*(2(q&1) + (s>>1)).
// This frees 70KB LDS: block LDS = weights+bias = 58.7KB -> 2 blocks/CU
// -> 32 waves/CU = 8 waves/SIMD (was 4) and the whole 512-block grid is
// co-resident (staging once, no serial second round).
// VGPR: bare __launch_bounds__(1024) caps alloc at 64 (R8 evidence) which
// is exactly the 8-waves/EU budget; x-prefetch dropped (TLP hides it).
// MFMA shapes, weight layouts, LN math, out stores: all R13-validated.
// prep unchanged. XCD swizzle kept: bid = q*128 + o*8 + c.
#define NTOK  32768
#define CIN   64
#define HDIM  128
#define O_CH  16
#define F2    16
#define SLOPE 0.01f
#define EPS   1e-5f

// LDS weight image (shorts). Rows 16B-aligned, 4-bank rotation/row.
#define SW0_STRIDE 72
#define SW1_STRIDE 136
#define SW2_STRIDE 136
#define SW0_OFF 0                       // 128 x 72  = 9216
#define SW1_OFF 9216                    // 128 x 136 = 17408
#define SW2_OFF (9216 + 17408)          // 16  x 136 = 2176
#define WIMG_SHORTS 28800               // 57600 B per o-channel
#define SBIAS_OFF WIMG_SHORTS           // bias floats after weights
#define SBIAS_FLOATS 272                // b0'(128) b1'(128) b2'(16)
#define SMEM_SHORTS (SBIAS_OFF + SBIAS_FLOATS * 2)  // 58688 B total

// d_ws layout (bytes); ~0.93 MB total (ws proven >= 33.5 MB).
#define WIMG_OFF   0
#define WIMG_BYTES ((size_t)O_CH * WIMG_SHORTS * 2)          // 921600
#define B0F_OFF    WIMG_BYTES
#define B0F_BYTES  ((size_t)O_CH * HDIM * 4)
#define B1F_OFF    (B0F_OFF + B0F_BYTES)
#define B1F_BYTES  ((size_t)O_CH * HDIM * 4)
#define B2F_OFF    (B1F_OFF + B1F_BYTES)

typedef __attribute__((ext_vector_type(8))) short bf16x8;
typedef __attribute__((ext_vector_type(4))) short bf16x4;
typedef __attribute__((ext_vector_type(4))) float f32x4;

__device__ __forceinline__ unsigned short f2b(float f) {
  union { float f; unsigned int i; } v;
  v.f = f;
  unsigned int i = v.i;
  unsigned int r = (i + 0x7fffu + ((i >> 16) & 1u)) >> 16;  // RNE
  return (unsigned short)r;
}
// native float->bf16 (RNE). [validated R10/R12/R13]
__device__ __forceinline__ unsigned short f2bn(float f) {
  union { __hip_bfloat16 h; unsigned short s; } v;
  v.h = __float2bfloat16(f);
  return v.s;
}
__device__ __forceinline__ float leaky(float t) {
  return fmaxf(t, SLOPE * t);   // == LeakyReLU for all finite t
}
__device__ __forceinline__ bf16x8 cvt8(const float* __restrict__ p) {
  float4 a = *(const float4*)p;
  float4 b = *(const float4*)(p + 4);
  bf16x8 r;
  r[0] = (short)f2b(a.x); r[1] = (short)f2b(a.y);
  r[2] = (short)f2b(a.z); r[3] = (short)f2b(a.w);
  r[4] = (short)f2b(b.x); r[5] = (short)f2b(b.y);
  r[6] = (short)f2b(b.z); r[7] = (short)f2b(b.w);
  return r;
}
__device__ __forceinline__ bf16x8 cvt8s(const float* __restrict__ p,
                                        const float* __restrict__ s) {
  bf16x8 r;
#pragma unroll
  for (int i = 0; i < 8; ++i) r[i] = (short)f2b(p[i] * s[i]);
  return r;
}

// leaky + LayerNorm on C-layout (col=token=lane&15, row=h=nt*16+quad*4+r).
// Stats: 4+4 parallel chains + tree (R13), butterfly xor 16,32 finishes the
// 128-sum. Output packed to registers (NOT LDS): pk01[nt] = bf16(h_r0)
// | bf16(h_r1)<<16, pk23[nt] = (r2,r3) — the h-pairs in ascending-h order,
// exactly the bytes the old SH store would have produced.
__device__ __forceinline__ void leaky_ln_pack(
    f32x4* acc, unsigned* pk01, unsigned* pk23) {
  float a0 = 0.f, a1 = 0.f, a2 = 0.f, a3 = 0.f;
  float c0 = 0.f, c1 = 0.f, c2 = 0.f, c3 = 0.f;
#pragma unroll
  for (int nt = 0; nt < 8; ++nt) {
    float t0 = leaky(acc[nt][0]);
    float t1 = leaky(acc[nt][1]);
    float t2 = leaky(acc[nt][2]);
    float t3 = leaky(acc[nt][3]);
    acc[nt][0] = t0; acc[nt][1] = t1; acc[nt][2] = t2; acc[nt][3] = t3;
    a0 += t0; a1 += t1; a2 += t2; a3 += t3;
    c0 = fmaf(t0, t0, c0); c1 = fmaf(t1, t1, c1);
    c2 = fmaf(t2, t2, c2); c3 = fmaf(t3, t3, c3);
  }
  float s1 = (a0 + a1) + (a2 + a3);
  float s2 = (c0 + c1) + (c2 + c3);
  s1 += __shfl_xor(s1, 16); s2 += __shfl_xor(s2, 16);
  s1 += __shfl_xor(s1, 32); s2 += __shfl_xor(s2, 32);
  float mu = s1 * (1.0f / 128.0f);
  float var = s2 * (1.0f / 128.0f) - mu * mu;
  float rs = rsqrtf(var + EPS);
  float nm = -mu * rs;                    // (v-mu)*rs == fma(v, rs, nm)
#pragma unroll
  for (int nt = 0; nt < 8; ++nt) {
    unsigned lo0 = f2bn(fmaf(acc[nt][0], rs, nm));
    unsigned hi0 = f2bn(fmaf(acc[nt][1], rs, nm));
    unsigned lo1 = f2bn(fmaf(acc[nt][2], rs, nm));
    unsigned hi1 = f2bn(fmaf(acc[nt][3], rs, nm));
    pk01[nt] = lo0 | (hi0 << 16);
    pk23[nt] = lo1 | (hi1 << 16);
  }
}

// Build the B-fragment bh[ks] (token=lo16, h=ks*32+quad*8+j, j=0..7) from
// the wave's packed LN output. Derivation (verified by example):
//   h = ks*32 + 8q + 2s (+1) -> owner nt' = 2ks + (q>>1)  [s-independent]
//   owner quad q' = 2(q&1) + (s>>1); pair = (s&1) ? pk23 : pk01.
// 8 shuffles (both nt' parities from both source lanes) + 4 selects.
__device__ __forceinline__ bf16x8 build_bh(
    const unsigned* pk01, const unsigned* pk23, int e, int o,
    int srcA, int srcB, bool hi32) {
  unsigned e01 = pk01[e], o01 = pk01[o];
  unsigned e23 = pk23[e], o23 = pk23[o];
  unsigned s1a = __shfl(e01, srcA, 64), s2a = __shfl(o01, srcA, 64);
  unsigned s3a = __shfl(e23, srcA, 64), s4a = __shfl(o23, srcA, 64);
  unsigned s1b = __shfl(e01, srcB, 64), s2b = __shfl(o01, srcB, 64);
  unsigned s3b = __shfl(e23, srcB, 64), s4b = __shfl(o23, srcB, 64);
  union { unsigned w[4]; bf16x8 v; } bh;
  bh.w[0] = hi32 ? s2a : s1a;   // j 0,1
  bh.w[1] = hi32 ? s4a : s3a;   // j 2,3
  bh.w[2] = hi32 ? s2b : s1b;   // j 4,5
  bh.w[3] = hi32 ? s4b : s3b;   // j 6,7
  return bh.v;
}

// prep: 16 blocks build per-o bf16 weight images with gamma folded and
// folded bias vectors. [byte-identical to R8/R10/R12/R13]
__global__ __launch_bounds__(256) void prep(
    const float* __restrict__ W0, const float* __restrict__ b0,
    const float* __restrict__ g0, const float* __restrict__ be0,
    const float* __restrict__ W1, const float* __restrict__ b1,
    const float* __restrict__ g1, const float* __restrict__ be1,
    const float* __restrict__ W2, const float* __restrict__ b2,
    unsigned short* __restrict__ wimg,
    float* __restrict__ b0f, float* __restrict__ b1f,
    float* __restrict__ b2f) {
  const int o = blockIdx.x, tid = threadIdx.x;
  __shared__ float sg0[HDIM], sbe0[HDIM], sg1[HDIM], sbe1[HDIM];
  if (tid < 128) {
    sg0[tid]  = g0 [o * HDIM + tid];
    sbe0[tid] = be0[o * HDIM + tid];
    sg1[tid]  = g1 [o * HDIM + tid];
    sbe1[tid] = be1[o * HDIM + tid];
  }
  __syncthreads();
  unsigned short* img = wimg + (size_t)o * WIMG_SHORTS;
  const float* w0 = W0 + (size_t)o * HDIM * CIN;
  for (int c = tid; c < (HDIM * CIN) / 8; c += 256) {
    int n = c >> 3, k8 = c & 7;
    *(bf16x8*)&img[SW0_OFF + n * SW0_STRIDE + k8 * 8] = cvt8(w0 + c * 8);
  }
  const float* w1 = W1 + (size_t)o * HDIM * HDIM;
  for (int c = tid; c < (HDIM * HDIM) / 8; c += 256) {
    int n = c >> 4, k8 = c & 15;
    *(bf16x8*)&img[SW1_OFF + n * SW1_STRIDE + k8 * 8] =
        cvt8s(w1 + c * 8, sg0 + k8 * 8);           // W1' = W1 * g0[k]
  }
  const float* w2 = W2 + (size_t)o * F2 * HDIM;
  for (int c = tid; c < (F2 * HDIM) / 8; c += 256) {
    int n = c >> 4, k8 = c & 15;
    *(bf16x8*)&img[SW2_OFF + n * SW2_STRIDE + k8 * 8] =
        cvt8s(w2 + c * 8, sg1 + k8 * 8);           // W2' = W2 * g1[k]
  }
  if (tid < 128) {
    b0f[o * HDIM + tid] = b0[o * HDIM + tid];
    float d = 0.f;
    const float* w1r = w1 + (size_t)tid * HDIM;
    for (int k = 0; k < HDIM; ++k) d += w1r[k] * sbe0[k];
    b1f[o * HDIM + tid] = b1[o * HDIM + tid] + d;  // b1' = b1 + W1*be0
  } else if (tid < 144) {
    int f = tid - 128;
    float d = 0.f;
    const float* w2r = w2 + (size_t)f * HDIM;
    for (int k = 0; k < HDIM; ++k) d += w2r[k] * sbe1[k];
    b2f[o * F2 + f] = b2[o * F2 + f] + d;          // b2' = b2 + W2*be1
  }
}

// film_main: block = one o x 1024 tokens (16 waves x 4 m-tiles).
// LDS = weights + bias only (58.7 KB) -> 2 blocks/CU -> 8 waves/SIMD at
// <=64 VGPR (bare launch_bounds(1024) caps alloc at 64 = the 8-wave/EU
// budget). No SH: h moves between layers via register exchange (build_bh).
// No cross-wave dependency; the only barrier is after weight staging.
// bid = q*128 + o*8 + c: 16 o-blocks of token-group tg=q*8+c co-resident
// on XCD c -> full-line write combining of the 4B/sector output stores.
__global__ __launch_bounds__(1024) void film_main(
    const float* __restrict__ x,
    const unsigned short* __restrict__ wimg,
    const float* __restrict__ b0f, const float* __restrict__ b1f,
    const float* __restrict__ b2f,
    float* __restrict__ out) {
  __shared__ unsigned short smem[SMEM_SHORTS];
  const int tid = threadIdx.x;
  const int c   = blockIdx.x & 7;
  const int o   = (blockIdx.x >> 3) & 15;
  const int q   = blockIdx.x >> 7;
  const int tok0 = (q * 8 + c) * 1024;

  {  // stage prebuilt 57.6 KB bf16 weight image (contiguous copy)
    const bf16x8* src = (const bf16x8*)(wimg + (size_t)o * WIMG_SHORTS);
    for (int i = tid; i < WIMG_SHORTS / 8; i += 1024)
      *(bf16x8*)&smem[i * 8] = src[i];
  }
  // stage folded bias vectors (272 floats) into LDS
  float* sbias = (float*)&smem[SBIAS_OFF];
  if (tid < 128)      sbias[tid] = b0f[o * HDIM + tid];
  else if (tid < 256) sbias[tid] = b1f[o * HDIM + (tid - 128)];
  else if (tid < 272) sbias[tid] = b2f[o * F2 + (tid - 256)];

  const int lane = tid & 63;
  const int wave = tid >> 6;        // 0..15
  const int lo16 = lane & 15;
  const int quad = lane >> 4;
  const bool hi32 = (lane & 32) != 0;           // quad>>1
  const int srcA = lo16 + ((quad & 1) << 5);    // lane of quad 2*(q&1)
  const int srcB = srcA + 16;                   // lane of quad 2*(q&1)+1
  const float* sb0 = sbias;
  const float* sb1 = sbias + HDIM;
  const float* sb2 = sbias + 2 * HDIM;
  __syncthreads();

  for (int mt = 0; mt < 4; ++mt) {
    const int trow = tok0 + wave * 64 + mt * 16;
    unsigned pk01[8], pk23[8];

    // ---- Layer 0: A=W0 (LDS), B=x tokens (fp32 -> bf16 native cvt)
    f32x4 acc[8];
#pragma unroll
    for (int nt = 0; nt < 8; ++nt)
      acc[nt] = *(const f32x4*)(sb0 + nt * 16 + quad * 4);
    {
      const float* xr = x + (size_t)(trow + lo16) * CIN + quad * 8;
#pragma unroll
      for (int ks = 0; ks < 2; ++ks) {
        float4 xa = *(const float4*)(xr + ks * 32);
        float4 xb = *(const float4*)(xr + ks * 32 + 4);
        bf16x8 bx;
        bx[0] = (short)f2bn(xa.x); bx[1] = (short)f2bn(xa.y);
        bx[2] = (short)f2bn(xa.z); bx[3] = (short)f2bn(xa.w);
        bx[4] = (short)f2bn(xb.x); bx[5] = (short)f2bn(xb.y);
        bx[6] = (short)f2bn(xb.z); bx[7] = (short)f2bn(xb.w);
#pragma unroll
        for (int nt = 0; nt < 8; ++nt) {
          bf16x8 a = *(const bf16x8*)
              &smem[SW0_OFF + (nt * 16 + lo16) * SW0_STRIDE + ks * 32 + quad * 8];
          acc[nt] = __builtin_amdgcn_mfma_f32_16x16x32_bf16(a, bx, acc[nt], 0, 0, 0);
        }
      }
    }
    leaky_ln_pack(acc, pk01, pk23);

    // ---- Layer 1: A=W1' (LDS), B=h0 via register exchange
#pragma unroll
    for (int nt = 0; nt < 8; ++nt)
      acc[nt] = *(const f32x4*)(sb1 + nt * 16 + quad * 4);
#pragma unroll
    for (int ks = 0; ks < 4; ++ks) {
      bf16x8 bh = build_bh(pk01, pk23, 2 * ks, 2 * ks + 1, srcA, srcB, hi32);
#pragma unroll
      for (int nt = 0; nt < 8; ++nt) {
        bf16x8 a = *(const bf16x8*)
            &smem[SW1_OFF + (nt * 16 + lo16) * SW1_STRIDE + ks * 32 + quad * 8];
        acc[nt] = __builtin_amdgcn_mfma_f32_16x16x32_bf16(a, bh, acc[nt], 0, 0, 0);
      }
    }
    leaky_ln_pack(acc, pk01, pk23);

    // ---- Layer 2: A=W2' (LDS), B=h1 via register exchange
    f32x4 acc2 = *(const f32x4*)(sb2 + quad * 4);
#pragma unroll
    for (int ks = 0; ks < 4; ++ks) {
      bf16x8 bh = build_bh(pk01, pk23, 2 * ks, 2 * ks + 1, srcA, srcB, hi32);
      bf16x8 a = *(const bf16x8*)
          &smem[SW2_OFF + lo16 * SW2_STRIDE + ks * 32 + quad * 8];
      acc2 = __builtin_amdgcn_mfma_f32_16x16x32_bf16(a, bh, acc2, 0, 0, 0);
    }
    // direct fp32 out[tok][f][o]: token=trow+lo16, f=quad*4+r, o fixed.
    {
      const size_t tb = (size_t)(trow + lo16) * (F2 * O_CH);
#pragma unroll
      for (int r = 0; r < 4; ++r)
        out[tb + (quad * 4 + r) * O_CH + o] = leaky(acc2[r]);
    }
  }
}

extern "C" void kernel_launch(void* const* d_in, const int* in_sizes, int n_in,
                              void* d_out, int out_size, void* d_ws, size_t ws_size,
                              hipStream_t stream) {
  (void)in_sizes; (void)n_in; (void)out_size; (void)ws_size;
  const float* x   = (const float*)d_in[0];
  const float* W0  = (const float*)d_in[1];
  const float* b0  = (const float*)d_in[2];
  const float* g0  = (const float*)d_in[3];
  const float* be0 = (const float*)d_in[4];
  const float* W1  = (const float*)d_in[5];
  const float* b1  = (const float*)d_in[6];
  const float* g1  = (const float*)d_in[7];
  const float* be1 = (const float*)d_in[8];
  const float* W2  = (const float*)d_in[9];
  const float* b2  = (const float*)d_in[10];

  unsigned short* wimg = (unsigned short*)((char*)d_ws + WIMG_OFF);
  float* b0f = (float*)((char*)d_ws + B0F_OFF);
  float* b1f = (float*)((char*)d_ws + B1F_OFF);
  float* b2f = (float*)((char*)d_ws + B2F_OFF);

  prep<<<dim3(O_CH), dim3(256), 0, stream>>>(
      W0, b0, g0, be0, W1, b1, g1, be1, W2, b2, wimg, b0f, b1f, b2f);
  film_main<<<dim3(O_CH * (NTOK / 1024)), dim3(1024), 0, stream>>>(
      x, wimg, b0f, b1f, b2f, (float*)d_out);
}

// Round 9
// 146.630 us; speedup vs baseline: 3.9521x; 3.9521x over previous
//
#include <hip/hip_runtime.h>
#include <hip/hip_bf16.h>

// FiLM block, MI355X. I/O fp32; compute bf16 MFMA (A=weights, B=tokens,
// C col=token), fp32 accum. R15 = R13's main loop VERBATIM (71us, best)
// with prep FUSED into film_main:
//  - R14's lesson: 8 waves/SIMD needs <=64 VGPR and the inter-layer h
//    state doesn't fit (FETCH 891MB of spills). SH-in-LDS at 4 waves/SIMD
//    is the validated structure; occupancy is a structural wall.
//  - prep's cost was real: its b1' fold is a SERIAL 128-iter global-latency
//    loop on 16 blocks (~10-15us) + launch gap + wimg HBM round-trip.
//    Each film block now builds its own o-weight image in LDS from global
//    (L2-hot: 16 images x 115KB fp32 = 1.8MB per XCD) and computes bias
//    folds with 1024-way-parallel partial dots + 3-level shfl_xor reduce.
//  - Weight image BITS identical to prep's (same cvt8/cvt8s helpers, same
//    layout); b1'/b2' differ only by fp32 reassociation (threshold has
//    3.8x headroom at absmax 0.0156).
// LDS 130.4KB (1 block/CU, 4 waves/SIMD, unchanged). Single launch.
// XCD swizzle kept: bid = q*128 + o*8 + c.
#define NTOK  32768
#define CIN   64
#define HDIM  128
#define O_CH  16
#define F2    16
#define SLOPE 0.01f
#define EPS   1e-5f

// LDS layout (shorts). Weight rows 16B-aligned, 4-bank rotation/row.
#define SW0_STRIDE 72
#define SW1_STRIDE 136
#define SW2_STRIDE 136
#define SH_STRIDE  136
#define SW0_OFF 0                       // 128 x 72  = 9216
#define SW1_OFF 9216                    // 128 x 136 = 17408
#define SW2_OFF (9216 + 17408)          // 16  x 136 = 2176
#define WIMG_SHORTS 28800               // 57600 B weight image
#define SH_OFF  28800                   // 256 rows x 136 (16 waves x 16)
#define SH_ROWS 256
#define SBIAS_OFF (SH_OFF + SH_ROWS * SH_STRIDE)    // 63616; 4B-aligned
#define SBIAS_FLOATS 272                 // b0'(128) b1'(128) b2'(16)
#define SGB_OFF (SBIAS_OFF + SBIAS_FLOATS * 2)      // 64160; 4B-aligned
#define SGB_FLOATS 512                   // g0,be0,g1,be1
#define SMEM_SHORTS (SGB_OFF + SGB_FLOATS * 2)      // 65184 sh = 130368 B

typedef __attribute__((ext_vector_type(8))) short bf16x8;
typedef __attribute__((ext_vector_type(4))) short bf16x4;
typedef __attribute__((ext_vector_type(4))) float f32x4;

__device__ __forceinline__ unsigned short f2b(float f) {
  union { float f; unsigned int i; } v;
  v.f = f;
  unsigned int i = v.i;
  unsigned int r = (i + 0x7fffu + ((i >> 16) & 1u)) >> 16;  // RNE
  return (unsigned short)r;
}
// native float->bf16 (RNE). [validated R10/R12/R13]
__device__ __forceinline__ short f2bn(float f) {
  union { __hip_bfloat16 h; short s; } v;
  v.h = __float2bfloat16(f);
  return v.s;
}
__device__ __forceinline__ float leaky(float t) {
  return fmaxf(t, SLOPE * t);   // == LeakyReLU for all finite t
}
__device__ __forceinline__ bf16x8 cvt8(const float* __restrict__ p) {
  float4 a = *(const float4*)p;
  float4 b = *(const float4*)(p + 4);
  bf16x8 r;
  r[0] = (short)f2b(a.x); r[1] = (short)f2b(a.y);
  r[2] = (short)f2b(a.z); r[3] = (short)f2b(a.w);
  r[4] = (short)f2b(b.x); r[5] = (short)f2b(b.y);
  r[6] = (short)f2b(b.z); r[7] = (short)f2b(b.w);
  return r;
}
__device__ __forceinline__ bf16x8 cvt8s(const float* __restrict__ p,
                                        const float* __restrict__ s) {
  bf16x8 r;
#pragma unroll
  for (int i = 0; i < 8; ++i) r[i] = (short)f2b(p[i] * s[i]);
  return r;
}

// leaky + LayerNorm on C-layout (col=token=lane&15, row=h). [R13 verbatim]
__device__ __forceinline__ void leaky_ln_store(
    f32x4* acc, unsigned short* __restrict__ sh,
    int row0, int lo16, int quad) {
  float a0 = 0.f, a1 = 0.f, a2 = 0.f, a3 = 0.f;
  float c0 = 0.f, c1 = 0.f, c2 = 0.f, c3 = 0.f;
#pragma unroll
  for (int nt = 0; nt < 8; ++nt) {
    float t0 = leaky(acc[nt][0]);
    float t1 = leaky(acc[nt][1]);
    float t2 = leaky(acc[nt][2]);
    float t3 = leaky(acc[nt][3]);
    acc[nt][0] = t0; acc[nt][1] = t1; acc[nt][2] = t2; acc[nt][3] = t3;
    a0 += t0; a1 += t1; a2 += t2; a3 += t3;
    c0 = fmaf(t0, t0, c0); c1 = fmaf(t1, t1, c1);
    c2 = fmaf(t2, t2, c2); c3 = fmaf(t3, t3, c3);
  }
  float s1 = (a0 + a1) + (a2 + a3);
  float s2 = (c0 + c1) + (c2 + c3);
  s1 += __shfl_xor(s1, 16); s2 += __shfl_xor(s2, 16);
  s1 += __shfl_xor(s1, 32); s2 += __shfl_xor(s2, 32);
  float mu = s1 * (1.0f / 128.0f);
  float var = s2 * (1.0f / 128.0f) - mu * mu;
  float rs = rsqrtf(var + EPS);
  float nm = -mu * rs;                    // (v-mu)*rs == fma(v, rs, nm)
  unsigned short* dst = sh + (row0 + lo16) * SH_STRIDE + quad * 4;
#pragma unroll
  for (int nt = 0; nt < 8; ++nt) {
    bf16x4 p;
    p[0] = f2bn(fmaf(acc[nt][0], rs, nm));
    p[1] = f2bn(fmaf(acc[nt][1], rs, nm));
    p[2] = f2bn(fmaf(acc[nt][2], rs, nm));
    p[3] = f2bn(fmaf(acc[nt][3], rs, nm));
    *(bf16x4*)(dst + nt * 16) = p;
  }
}

// film_main: block = one o x 1024 tokens (16 waves x 4 m-tiles), 1 block/CU
// (130.4 KB LDS) -> 4 waves/SIMD; waves_per_eu(4,4) budget = 128 VGPRs.
// Staging phase (fused prep): gamma/beta -> LDS; weight image built from
// global fp32 (L2-hot) with gamma folded; bias folds 1024-way parallel.
// Main loop: R13 verbatim (x-prefetch, striped LN, SH hand-off).
__global__ __launch_bounds__(1024)
__attribute__((amdgpu_waves_per_eu(4, 4))) void film_main(
    const float* __restrict__ x,
    const float* __restrict__ W0, const float* __restrict__ b0,
    const float* __restrict__ g0, const float* __restrict__ be0,
    const float* __restrict__ W1, const float* __restrict__ b1,
    const float* __restrict__ g1, const float* __restrict__ be1,
    const float* __restrict__ W2, const float* __restrict__ b2,
    float* __restrict__ out) {
  __shared__ unsigned short smem[SMEM_SHORTS];
  const int tid = threadIdx.x;
  const int c   = blockIdx.x & 7;
  const int o   = (blockIdx.x >> 3) & 15;
  const int q   = blockIdx.x >> 7;
  const int tok0 = (q * 8 + c) * 1024;

  float* sbias = (float*)&smem[SBIAS_OFF];
  float* sgb   = (float*)&smem[SGB_OFF];
  float* sg0v  = sgb;
  float* sbe0v = sgb + 128;
  float* sg1v  = sgb + 256;
  float* sbe1v = sgb + 384;

  // ---- staging 1: gamma/beta fp32 into LDS
  if (tid < 128)      sg0v [tid]       = g0 [o * HDIM + tid];
  else if (tid < 256) sbe0v[tid - 128] = be0[o * HDIM + (tid - 128)];
  else if (tid < 384) sg1v [tid - 256] = g1 [o * HDIM + (tid - 256)];
  else if (tid < 512) sbe1v[tid - 384] = be1[o * HDIM + (tid - 384)];
  __syncthreads();

  // ---- staging 2: build weight image (bits identical to prep's) + biases
  const float* w0 = W0 + (size_t)o * HDIM * CIN;
  const float* w1 = W1 + (size_t)o * HDIM * HDIM;
  const float* w2 = W2 + (size_t)o * F2 * HDIM;
  {  // W0: 1024 chunks of 8, one per thread
    int cc = tid, n = cc >> 3, k8 = cc & 7;
    *(bf16x8*)&smem[SW0_OFF + n * SW0_STRIDE + k8 * 8] = cvt8(w0 + cc * 8);
  }
#pragma unroll
  for (int rep = 0; rep < 2; ++rep) {  // W1: 2048 chunks, two per thread
    int cc = tid + rep * 1024, n = cc >> 4, k8 = cc & 15;
    *(bf16x8*)&smem[SW1_OFF + n * SW1_STRIDE + k8 * 8] =
        cvt8s(w1 + cc * 8, sg0v + k8 * 8);         // W1' = W1 * g0[k]
  }
  if (tid < 256) {  // W2: 256 chunks
    int cc = tid, n = cc >> 4, k8 = cc & 15;
    *(bf16x8*)&smem[SW2_OFF + n * SW2_STRIDE + k8 * 8] =
        cvt8s(w2 + cc * 8, sg1v + k8 * 8);         // W2' = W2 * g1[k]
  }
  if (tid < 128) sbias[tid] = b0[o * HDIM + tid];  // b0' = b0
  {  // b1' = b1 + W1*be0 : 8 threads per h-row, 16-elem partials + reduce
    int h = tid >> 3, seg = tid & 7;
    const float* w1r = w1 + (size_t)h * HDIM + seg * 16;
    const float* bev = sbe0v + seg * 16;
    float p = 0.f;
#pragma unroll
    for (int k = 0; k < 16; ++k) p = fmaf(w1r[k], bev[k], p);
    p += __shfl_xor(p, 1); p += __shfl_xor(p, 2); p += __shfl_xor(p, 4);
    if (seg == 0) sbias[HDIM + h] = b1[o * HDIM + h] + p;
  }
  if (tid < 128) {  // b2' = b2 + W2*be1 : 8 threads per f-row
    int f = tid >> 3, seg = tid & 7;
    const float* w2r = w2 + (size_t)f * HDIM + seg * 16;
    const float* bev = sbe1v + seg * 16;
    float p = 0.f;
#pragma unroll
    for (int k = 0; k < 16; ++k) p = fmaf(w2r[k], bev[k], p);
    p += __shfl_xor(p, 1); p += __shfl_xor(p, 2); p += __shfl_xor(p, 4);
    if (seg == 0) sbias[2 * HDIM + f] = b2[o * F2 + f] + p;
  }

  const int lane = tid & 63;
  const int wave = tid >> 6;        // 0..15
  const int lo16 = lane & 15;
  const int quad = lane >> 4;
  const int row0 = wave * 16;
  const float* sb0 = sbias;
  const float* sb1 = sbias + HDIM;
  const float* sb2 = sbias + 2 * HDIM;

  // x software pipeline: preload mt=0's 4 float4 before the barrier. [R13]
  const int tbase = tok0 + wave * 64;
  const float* xw = x + (size_t)(tbase + lo16) * CIN + quad * 8;
  float4 xa0 = *(const float4*)(xw);
  float4 xb0 = *(const float4*)(xw + 4);
  float4 xa1 = *(const float4*)(xw + 32);
  float4 xb1 = *(const float4*)(xw + 36);
  __syncthreads();

  for (int mt = 0; mt < 4; ++mt) {
    const int trow = tbase + mt * 16;

    // convert current x to bf16 B-fragments (RNE, native cvt)
    bf16x8 bx0, bx1;
    bx0[0] = f2bn(xa0.x); bx0[1] = f2bn(xa0.y);
    bx0[2] = f2bn(xa0.z); bx0[3] = f2bn(xa0.w);
    bx0[4] = f2bn(xb0.x); bx0[5] = f2bn(xb0.y);
    bx0[6] = f2bn(xb0.z); bx0[7] = f2bn(xb0.w);
    bx1[0] = f2bn(xa1.x); bx1[1] = f2bn(xa1.y);
    bx1[2] = f2bn(xa1.z); bx1[3] = f2bn(xa1.w);
    bx1[4] = f2bn(xb1.x); bx1[5] = f2bn(xb1.y);
    bx1[6] = f2bn(xb1.z); bx1[7] = f2bn(xb1.w);
    // issue next m-tile's loads now; latency hides under L0+LN0+L1
    if (mt < 3) {
      const float* xn = xw + (size_t)(mt + 1) * 16 * CIN;
      xa0 = *(const float4*)(xn);
      xb0 = *(const float4*)(xn + 4);
      xa1 = *(const float4*)(xn + 32);
      xb1 = *(const float4*)(xn + 36);
    }

    // ---- Layer 0: A=W0 (LDS), B=x tokens
    f32x4 acc[8];
#pragma unroll
    for (int nt = 0; nt < 8; ++nt)
      acc[nt] = *(const f32x4*)(sb0 + nt * 16 + quad * 4);
#pragma unroll
    for (int nt = 0; nt < 8; ++nt) {
      bf16x8 a = *(const bf16x8*)
          &smem[SW0_OFF + (nt * 16 + lo16) * SW0_STRIDE + quad * 8];
      acc[nt] = __builtin_amdgcn_mfma_f32_16x16x32_bf16(a, bx0, acc[nt], 0, 0, 0);
    }
#pragma unroll
    for (int nt = 0; nt < 8; ++nt) {
      bf16x8 a = *(const bf16x8*)
          &smem[SW0_OFF + (nt * 16 + lo16) * SW0_STRIDE + 32 + quad * 8];
      acc[nt] = __builtin_amdgcn_mfma_f32_16x16x32_bf16(a, bx1, acc[nt], 0, 0, 0);
    }
    leaky_ln_store(acc, smem + SH_OFF, row0, lo16, quad);

    // ---- Layer 1: A=W1' (LDS), B=h
#pragma unroll
    for (int nt = 0; nt < 8; ++nt)
      acc[nt] = *(const f32x4*)(sb1 + nt * 16 + quad * 4);
#pragma unroll
    for (int ks = 0; ks < 4; ++ks) {
      bf16x8 bh = *(const bf16x8*)
          &smem[SH_OFF + (row0 + lo16) * SH_STRIDE + ks * 32 + quad * 8];
#pragma unroll
      for (int nt = 0; nt < 8; ++nt) {
        bf16x8 a = *(const bf16x8*)
            &smem[SW1_OFF + (nt * 16 + lo16) * SW1_STRIDE + ks * 32 + quad * 8];
        acc[nt] = __builtin_amdgcn_mfma_f32_16x16x32_bf16(a, bh, acc[nt], 0, 0, 0);
      }
    }
    leaky_ln_store(acc, smem + SH_OFF, row0, lo16, quad);

    // ---- Layer 2: A=W2' (LDS), B=h -> C[col=token][row=f]
    f32x4 acc2 = *(const f32x4*)(sb2 + quad * 4);
#pragma unroll
    for (int ks = 0; ks < 4; ++ks) {
      bf16x8 bh = *(const bf16x8*)
          &smem[SH_OFF + (row0 + lo16) * SH_STRIDE + ks * 32 + quad * 8];
      bf16x8 a = *(const bf16x8*)
          &smem[SW2_OFF + lo16 * SW2_STRIDE + ks * 32 + quad * 8];
      acc2 = __builtin_amdgcn_mfma_f32_16x16x32_bf16(a, bh, acc2, 0, 0, 0);
    }
    // direct fp32 out[tok][f][o]: token=trow+lo16, f=quad*4+r, o fixed.
    {
      const size_t tb = (size_t)(trow + lo16) * (F2 * O_CH);
#pragma unroll
      for (int r = 0; r < 4; ++r)
        out[tb + (quad * 4 + r) * O_CH + o] = leaky(acc2[r]);
    }
  }
}

extern "C" void kernel_launch(void* const* d_in, const int* in_sizes, int n_in,
                              void* d_out, int out_size, void* d_ws, size_t ws_size,
                              hipStream_t stream) {
  (void)in_sizes; (void)n_in; (void)out_size; (void)d_ws; (void)ws_size;
  const float* x   = (const float*)d_in[0];
  const float* W0  = (const float*)d_in[1];
  const float* b0  = (const float*)d_in[2];
  const float* g0  = (const float*)d_in[3];
  const float* be0 = (const float*)d_in[4];
  const float* W1  = (const float*)d_in[5];
  const float* b1  = (const float*)d_in[6];
  const float* g1  = (const float*)d_in[7];
  const float* be1 = (const float*)d_in[8];
  const float* W2  = (const float*)d_in[9];
  const float* b2  = (const float*)d_in[10];

  film_main<<<dim3(O_CH * (NTOK / 1024)), dim3(1024), 0, stream>>>(
      x, W0, b0, g0, be0, W1, b1, g1, be1, W2, b2, (float*)d_out);
}

// Round 10
// 141.393 us; speedup vs baseline: 4.0984x; 1.0370x over previous
//
#include <hip/hip_runtime.h>
#include <hip/hip_bf16.h>

// FiLM block, MI355X. I/O fp32; compute bf16 MFMA (A=weights, B=tokens,
// C col=token), fp32 accum. R16 = R15 (fused prep, passed, film 75us) +:
//  (1) mt 4->8, grid 512->256: each CU ran 2 blocks serially, staging the
//      57.6KB weight image + bias folds TWICE. Now 2048 tokens/block, all
//      256 blocks co-resident, one staging per CU.
//  (2) packed-f32 LN elementwise math (float2 ext-vectors -> v_pk_*_f32):
//      leaky = max(t,0) + SLOPE*min(t,0) (exact), packed sums and
//      normalize. ~Halves LN elementwise VALU instruction count.
//      __builtin_elementwise_max/min guarded by __has_builtin with scalar
//      fallback (no unverified-API compile risk).
//  (3) R9 lesson: total-minus-film ~71us is FIXED harness overhead (gap
//      persisted with zero prep kernel) -> only film_main matters.
// MFMA loops, SH hand-off, striped stats, x-prefetch: R13/R15 verbatim.
// XCD swizzle kept: bid = q*128 + o*8 + c (q now 0..1).
#define NTOK  32768
#define CIN   64
#define HDIM  128
#define O_CH  16
#define F2    16
#define MT    8
#define SLOPE 0.01f
#define EPS   1e-5f

// LDS layout (shorts). Weight rows 16B-aligned, 4-bank rotation/row.
#define SW0_STRIDE 72
#define SW1_STRIDE 136
#define SW2_STRIDE 136
#define SH_STRIDE  136
#define SW0_OFF 0                       // 128 x 72  = 9216
#define SW1_OFF 9216                    // 128 x 136 = 17408
#define SW2_OFF (9216 + 17408)          // 16  x 136 = 2176
#define WIMG_SHORTS 28800               // 57600 B weight image
#define SH_OFF  28800                   // 256 rows x 136 (16 waves x 16)
#define SH_ROWS 256
#define SBIAS_OFF (SH_OFF + SH_ROWS * SH_STRIDE)    // 63616; 4B-aligned
#define SBIAS_FLOATS 272                 // b0'(128) b1'(128) b2'(16)
#define SGB_OFF (SBIAS_OFF + SBIAS_FLOATS * 2)      // 64160; 4B-aligned
#define SGB_FLOATS 512                   // g0,be0,g1,be1
#define SMEM_SHORTS (SGB_OFF + SGB_FLOATS * 2)      // 65184 sh = 130368 B

typedef __attribute__((ext_vector_type(8))) short bf16x8;
typedef __attribute__((ext_vector_type(4))) short bf16x4;
typedef __attribute__((ext_vector_type(4))) float f32x4;
typedef __attribute__((ext_vector_type(2))) float f32x2;

__device__ __forceinline__ unsigned short f2b(float f) {
  union { float f; unsigned int i; } v;
  v.f = f;
  unsigned int i = v.i;
  unsigned int r = (i + 0x7fffu + ((i >> 16) & 1u)) >> 16;  // RNE
  return (unsigned short)r;
}
// native float->bf16 (RNE). [validated R10/R12/R13]
__device__ __forceinline__ short f2bn(float f) {
  union { __hip_bfloat16 h; short s; } v;
  v.h = __float2bfloat16(f);
  return v.s;
}
__device__ __forceinline__ float leaky(float t) {
  return fmaxf(t, SLOPE * t);   // == LeakyReLU for all finite t
}
// packed leaky on 2 lanes: max(t,0) + SLOPE*min(t,0)  (exact LeakyReLU)
__device__ __forceinline__ f32x2 leaky2(f32x2 t) {
#if __has_builtin(__builtin_elementwise_max) && __has_builtin(__builtin_elementwise_min)
  f32x2 z = {0.f, 0.f};
  f32x2 pos = __builtin_elementwise_max(t, z);
  f32x2 neg = __builtin_elementwise_min(t, z);
  return pos + SLOPE * neg;          // v_pk_fma_f32
#else
  f32x2 r;
  r.x = fmaxf(t.x, SLOPE * t.x);
  r.y = fmaxf(t.y, SLOPE * t.y);
  return r;
#endif
}
__device__ __forceinline__ bf16x8 cvt8(const float* __restrict__ p) {
  float4 a = *(const float4*)p;
  float4 b = *(const float4*)(p + 4);
  bf16x8 r;
  r[0] = (short)f2b(a.x); r[1] = (short)f2b(a.y);
  r[2] = (short)f2b(a.z); r[3] = (short)f2b(a.w);
  r[4] = (short)f2b(b.x); r[5] = (short)f2b(b.y);
  r[6] = (short)f2b(b.z); r[7] = (short)f2b(b.w);
  return r;
}
__device__ __forceinline__ bf16x8 cvt8s(const float* __restrict__ p,
                                        const float* __restrict__ s) {
  bf16x8 r;
#pragma unroll
  for (int i = 0; i < 8; ++i) r[i] = (short)f2b(p[i] * s[i]);
  return r;
}

// leaky + LayerNorm on C-layout (col=token=lane&15, row=h). Packed-f32
// elementwise (v_pk_*), 2+2 f32x2 accumulator chains + tree (same depth as
// R13's 4 scalars, half the instructions), butterfly xor 16,32 finishes the
// 128-sum. Stores bf16 to LDS h[token][h] via ds_write_b64.
__device__ __forceinline__ void leaky_ln_store(
    f32x4* acc, unsigned short* __restrict__ sh,
    int row0, int lo16, int quad) {
  f32x2 sa = {0.f, 0.f}, sb = {0.f, 0.f};
  f32x2 qa = {0.f, 0.f}, qb = {0.f, 0.f};
#pragma unroll
  for (int nt = 0; nt < 8; ++nt) {
    f32x2 u0 = {acc[nt][0], acc[nt][1]};
    f32x2 u1 = {acc[nt][2], acc[nt][3]};
    u0 = leaky2(u0);
    u1 = leaky2(u1);
    acc[nt][0] = u0.x; acc[nt][1] = u0.y;
    acc[nt][2] = u1.x; acc[nt][3] = u1.y;
    sa += u0; sb += u1;          // v_pk_add_f32
    qa += u0 * u0;               // contracts to v_pk_fma_f32
    qb += u1 * u1;
  }
  float s1 = (sa.x + sa.y) + (sb.x + sb.y);
  float s2 = (qa.x + qa.y) + (qb.x + qb.y);
  s1 += __shfl_xor(s1, 16); s2 += __shfl_xor(s2, 16);
  s1 += __shfl_xor(s1, 32); s2 += __shfl_xor(s2, 32);
  float mu = s1 * (1.0f / 128.0f);
  float var = s2 * (1.0f / 128.0f) - mu * mu;
  float rs = rsqrtf(var + EPS);
  float nm = -mu * rs;                    // (v-mu)*rs == fma(v, rs, nm)
  const f32x2 rs2 = {rs, rs}, nm2 = {nm, nm};
  unsigned short* dst = sh + (row0 + lo16) * SH_STRIDE + quad * 4;
#pragma unroll
  for (int nt = 0; nt < 8; ++nt) {
    f32x2 u0 = {acc[nt][0], acc[nt][1]};
    f32x2 u1 = {acc[nt][2], acc[nt][3]};
    u0 = u0 * rs2 + nm2;         // v_pk_fma_f32
    u1 = u1 * rs2 + nm2;
    bf16x4 p;
    p[0] = f2bn(u0.x); p[1] = f2bn(u0.y);
    p[2] = f2bn(u1.x); p[3] = f2bn(u1.y);
    *(bf16x4*)(dst + nt * 16) = p;
  }
}

// film_main: block = one o x 2048 tokens (16 waves x 8 m-tiles), 1 block/CU
// (130.4 KB LDS) -> 4 waves/SIMD; waves_per_eu(4,4) budget = 128 VGPRs.
// 256 blocks co-resident: weight staging happens exactly once per CU.
// Staging (fused prep): gamma/beta -> LDS; weight image built from global
// fp32 (L2-hot) with gamma folded; bias folds 1024-way parallel.
__global__ __launch_bounds__(1024)
__attribute__((amdgpu_waves_per_eu(4, 4))) void film_main(
    const float* __restrict__ x,
    const float* __restrict__ W0, const float* __restrict__ b0,
    const float* __restrict__ g0, const float* __restrict__ be0,
    const float* __restrict__ W1, const float* __restrict__ b1,
    const float* __restrict__ g1, const float* __restrict__ be1,
    const float* __restrict__ W2, const float* __restrict__ b2,
    float* __restrict__ out) {
  __shared__ unsigned short smem[SMEM_SHORTS];
  const int tid = threadIdx.x;
  const int c   = blockIdx.x & 7;
  const int o   = (blockIdx.x >> 3) & 15;
  const int q   = blockIdx.x >> 7;              // 0..1
  const int tok0 = (q * 8 + c) * (16 * 16 * MT);

  float* sbias = (float*)&smem[SBIAS_OFF];
  float* sgb   = (float*)&smem[SGB_OFF];
  float* sg0v  = sgb;
  float* sbe0v = sgb + 128;
  float* sg1v  = sgb + 256;
  float* sbe1v = sgb + 384;

  // ---- staging 1: gamma/beta fp32 into LDS
  if (tid < 128)      sg0v [tid]       = g0 [o * HDIM + tid];
  else if (tid < 256) sbe0v[tid - 128] = be0[o * HDIM + (tid - 128)];
  else if (tid < 384) sg1v [tid - 256] = g1 [o * HDIM + (tid - 256)];
  else if (tid < 512) sbe1v[tid - 384] = be1[o * HDIM + (tid - 384)];
  __syncthreads();

  // ---- staging 2: build weight image (bits identical to prep's) + biases
  const float* w0 = W0 + (size_t)o * HDIM * CIN;
  const float* w1 = W1 + (size_t)o * HDIM * HDIM;
  const float* w2 = W2 + (size_t)o * F2 * HDIM;
  {  // W0: 1024 chunks of 8, one per thread
    int cc = tid, n = cc >> 3, k8 = cc & 7;
    *(bf16x8*)&smem[SW0_OFF + n * SW0_STRIDE + k8 * 8] = cvt8(w0 + cc * 8);
  }
#pragma unroll
  for (int rep = 0; rep < 2; ++rep) {  // W1: 2048 chunks, two per thread
    int cc = tid + rep * 1024, n = cc >> 4, k8 = cc & 15;
    *(bf16x8*)&smem[SW1_OFF + n * SW1_STRIDE + k8 * 8] =
        cvt8s(w1 + cc * 8, sg0v + k8 * 8);         // W1' = W1 * g0[k]
  }
  if (tid < 256) {  // W2: 256 chunks
    int cc = tid, n = cc >> 4, k8 = cc & 15;
    *(bf16x8*)&smem[SW2_OFF + n * SW2_STRIDE + k8 * 8] =
        cvt8s(w2 + cc * 8, sg1v + k8 * 8);         // W2' = W2 * g1[k]
  }
  if (tid < 128) sbias[tid] = b0[o * HDIM + tid];  // b0' = b0
  {  // b1' = b1 + W1*be0 : 8 threads per h-row, 16-elem partials + reduce
    int h = tid >> 3, seg = tid & 7;
    const float* w1r = w1 + (size_t)h * HDIM + seg * 16;
    const float* bev = sbe0v + seg * 16;
    float p = 0.f;
#pragma unroll
    for (int k = 0; k < 16; ++k) p = fmaf(w1r[k], bev[k], p);
    p += __shfl_xor(p, 1); p += __shfl_xor(p, 2); p += __shfl_xor(p, 4);
    if (seg == 0) sbias[HDIM + h] = b1[o * HDIM + h] + p;
  }
  if (tid < 128) {  // b2' = b2 + W2*be1 : 8 threads per f-row
    int f = tid >> 3, seg = tid & 7;
    const float* w2r = w2 + (size_t)f * HDIM + seg * 16;
    const float* bev = sbe1v + seg * 16;
    float p = 0.f;
#pragma unroll
    for (int k = 0; k < 16; ++k) p = fmaf(w2r[k], bev[k], p);
    p += __shfl_xor(p, 1); p += __shfl_xor(p, 2); p += __shfl_xor(p, 4);
    if (seg == 0) sbias[2 * HDIM + f] = b2[o * F2 + f] + p;
  }

  const int lane = tid & 63;
  const int wave = tid >> 6;        // 0..15
  const int lo16 = lane & 15;
  const int quad = lane >> 4;
  const int row0 = wave * 16;
  const float* sb0 = sbias;
  const float* sb1 = sbias + HDIM;
  const float* sb2 = sbias + 2 * HDIM;

  // x software pipeline: preload mt=0's 4 float4 before the barrier. [R13]
  const int tbase = tok0 + wave * (16 * MT);
  const float* xw = x + (size_t)(tbase + lo16) * CIN + quad * 8;
  float4 xa0 = *(const float4*)(xw);
  float4 xb0 = *(const float4*)(xw + 4);
  float4 xa1 = *(const float4*)(xw + 32);
  float4 xb1 = *(const float4*)(xw + 36);
  __syncthreads();

  for (int mt = 0; mt < MT; ++mt) {
    const int trow = tbase + mt * 16;

    // convert current x to bf16 B-fragments (RNE, native cvt)
    bf16x8 bx0, bx1;
    bx0[0] = f2bn(xa0.x); bx0[1] = f2bn(xa0.y);
    bx0[2] = f2bn(xa0.z); bx0[3] = f2bn(xa0.w);
    bx0[4] = f2bn(xb0.x); bx0[5] = f2bn(xb0.y);
    bx0[6] = f2bn(xb0.z); bx0[7] = f2bn(xb0.w);
    bx1[0] = f2bn(xa1.x); bx1[1] = f2bn(xa1.y);
    bx1[2] = f2bn(xa1.z); bx1[3] = f2bn(xa1.w);
    bx1[4] = f2bn(xb1.x); bx1[5] = f2bn(xb1.y);
    bx1[6] = f2bn(xb1.z); bx1[7] = f2bn(xb1.w);
    // issue next m-tile's loads now; latency hides under L0+LN0+L1
    if (mt < MT - 1) {
      const float* xn = xw + (size_t)(mt + 1) * 16 * CIN;
      xa0 = *(const float4*)(xn);
      xb0 = *(const float4*)(xn + 4);
      xa1 = *(const float4*)(xn + 32);
      xb1 = *(const float4*)(xn + 36);
    }

    // ---- Layer 0: A=W0 (LDS), B=x tokens
    f32x4 acc[8];
#pragma unroll
    for (int nt = 0; nt < 8; ++nt)
      acc[nt] = *(const f32x4*)(sb0 + nt * 16 + quad * 4);
#pragma unroll
    for (int nt = 0; nt < 8; ++nt) {
      bf16x8 a = *(const bf16x8*)
          &smem[SW0_OFF + (nt * 16 + lo16) * SW0_STRIDE + quad * 8];
      acc[nt] = __builtin_amdgcn_mfma_f32_16x16x32_bf16(a, bx0, acc[nt], 0, 0, 0);
    }
#pragma unroll
    for (int nt = 0; nt < 8; ++nt) {
      bf16x8 a = *(const bf16x8*)
          &smem[SW0_OFF + (nt * 16 + lo16) * SW0_STRIDE + 32 + quad * 8];
      acc[nt] = __builtin_amdgcn_mfma_f32_16x16x32_bf16(a, bx1, acc[nt], 0, 0, 0);
    }
    leaky_ln_store(acc, smem + SH_OFF, row0, lo16, quad);

    // ---- Layer 1: A=W1' (LDS), B=h
#pragma unroll
    for (int nt = 0; nt < 8; ++nt)
      acc[nt] = *(const f32x4*)(sb1 + nt * 16 + quad * 4);
#pragma unroll
    for (int ks = 0; ks < 4; ++ks) {
      bf16x8 bh = *(const bf16x8*)
          &smem[SH_OFF + (row0 + lo16) * SH_STRIDE + ks * 32 + quad * 8];
#pragma unroll
      for (int nt = 0; nt < 8; ++nt) {
        bf16x8 a = *(const bf16x8*)
            &smem[SW1_OFF + (nt * 16 + lo16) * SW1_STRIDE + ks * 32 + quad * 8];
        acc[nt] = __builtin_amdgcn_mfma_f32_16x16x32_bf16(a, bh, acc[nt], 0, 0, 0);
      }
    }
    leaky_ln_store(acc, smem + SH_OFF, row0, lo16, quad);

    // ---- Layer 2: A=W2' (LDS), B=h -> C[col=token][row=f]
    f32x4 acc2 = *(const f32x4*)(sb2 + quad * 4);
#pragma unroll
    for (int ks = 0; ks < 4; ++ks) {
      bf16x8 bh = *(const bf16x8*)
          &smem[SH_OFF + (row0 + lo16) * SH_STRIDE + ks * 32 + quad * 8];
      bf16x8 a = *(const bf16x8*)
          &smem[SW2_OFF + lo16 * SW2_STRIDE + ks * 32 + quad * 8];
      acc2 = __builtin_amdgcn_mfma_f32_16x16x32_bf16(a, bh, acc2, 0, 0, 0);
    }
    // direct fp32 out[tok][f][o]: token=trow+lo16, f=quad*4+r, o fixed.
    {
      const size_t tb = (size_t)(trow + lo16) * (F2 * O_CH);
#pragma unroll
      for (int r = 0; r < 4; ++r)
        out[tb + (quad * 4 + r) * O_CH + o] = leaky(acc2[r]);
    }
  }
}

extern "C" void kernel_launch(void* const* d_in, const int* in_sizes, int n_in,
                              void* d_out, int out_size, void* d_ws, size_t ws_size,
                              hipStream_t stream) {
  (void)in_sizes; (void)n_in; (void)out_size; (void)d_ws; (void)ws_size;
  const float* x   = (const float*)d_in[0];
  const float* W0  = (const float*)d_in[1];
  const float* b0  = (const float*)d_in[2];
  const float* g0  = (const float*)d_in[3];
  const float* be0 = (const float*)d_in[4];
  const float* W1  = (const float*)d_in[5];
  const float* b1  = (const float*)d_in[6];
  const float* g1  = (const float*)d_in[7];
  const float* be1 = (const float*)d_in[8];
  const float* W2  = (const float*)d_in[9];
  const float* b2  = (const float*)d_in[10];

  film_main<<<dim3(O_CH * (NTOK / (16 * 16 * MT))), dim3(1024), 0, stream>>>(
      x, W0, b0, g0, be0, W1, b1, g1, be1, W2, b2, (float*)d_out);
}